// Round 5
// baseline (509.292 us; speedup 1.0000x reference)
//
#include <hip/hip_runtime.h>
#include <hip/hip_bf16.h>

#define NTOT 1048576
#define NSEG 4096
#define HDIM 128
#define ODIM 256
#define BN   64
#define GRID1 1024
#define TPB  (NTOT / (BN * GRID1))   // 16 tiles per block

typedef __attribute__((ext_vector_type(8))) short bf16x8;
typedef __attribute__((ext_vector_type(4))) float f32x4;
typedef __attribute__((ext_vector_type(2))) unsigned int u32x2;

__device__ __forceinline__ unsigned short f32_to_bf16_rne(float f) {
    unsigned int u = __builtin_bit_cast(unsigned int, f);
    unsigned int r = (u + 0x7fffu + ((u >> 16) & 1u)) >> 16;
    return (unsigned short)r;
}
__device__ __forceinline__ unsigned int pk_bf16(float lo, float hi) {
    return ((unsigned int)f32_to_bf16_rne(hi) << 16) | f32_to_bf16_rne(lo);
}

// zero sumx (1M floats) + convert W1 (32768 f32 -> 16384 packed u32), one dispatch
__global__ void zero_convert(const float* __restrict__ W1, unsigned int* __restrict__ W1b,
                             float* __restrict__ sumx) {
    int gid = blockIdx.x * 256 + threadIdx.x;
    sumx[gid] = 0.0f;
    if (gid < (ODIM * HDIM / 2)) {
        float2 v = *(const float2*)(W1 + 2 * gid);
        W1b[gid] = pk_bf16(v.x, v.y);
    }
}

// Persistent pipelined stage1. Per iter:
//   MFMA(tile g from LDS[cur])  ->  sched_barrier  ->  issue x(g+1) loads ->
//   tanh + in-reg segreduce (loads in flight)  ->  cvt+ds_write LDS[cur^1] -> barrier.
// Prefetch regs (pf[8]=32 VGPR) deliberately NOT live during MFMA phase (R4 spilled).
__global__ __launch_bounds__(256, 4)
void stage1(const float* __restrict__ x, const int* __restrict__ batch,
            const unsigned short* __restrict__ W1b, const float* __restrict__ b1,
            float* __restrict__ sumx) {
    __shared__ __align__(16) unsigned char smem[2][BN * 256];  // 2 x 16KB swizzled bf16 A-tiles
    __shared__ int seg[2][BN];

    const int t    = threadIdx.x;
    const int lane = t & 63;
    const int wv   = t >> 6;
    const int l15  = lane & 15;
    const int lhi  = lane >> 4;

    // dtype probe: int64 little-endian => odd words (high words) are 0
    const bool is64 = (batch[NTOT - 1] == 0);
    const long tile0 = (long)blockIdx.x * TPB;

    float bias[4];
    #pragma unroll
    for (int nf = 0; nf < 4; ++nf) bias[nf] = b1[wv * 64 + nf * 16 + l15];

    // ---- prologue: stage tile0 into buf 0 ----
    {
        const long n0 = tile0 * BN;
        float4 pf[8];
        #pragma unroll
        for (int i = 0; i < 8; ++i) {
            int idx = i * 256 + t; int row = idx >> 5; int c4 = idx & 31;
            pf[i] = *(const float4*)(x + (n0 + row) * HDIM + c4 * 4);
        }
        int sv = 0;
        if (t < BN) sv = batch[is64 ? 2 * (n0 + t) : (n0 + t)];
        #pragma unroll
        for (int i = 0; i < 8; ++i) {
            int idx = i * 256 + t; int row = idx >> 5; int c4 = idx & 31;
            u32x2 p; p.x = pk_bf16(pf[i].x, pf[i].y); p.y = pk_bf16(pf[i].z, pf[i].w);
            int boff = row * 256 + ((c4 * 8) ^ ((row & 7) << 4));
            *(u32x2*)(&smem[0][0] + boff) = p;
        }
        if (t < BN) seg[0][t] = sv;
        __syncthreads();
    }

    int cur = 0;
    for (int g = 0; g < TPB; ++g) {
        const bool more = (g + 1 < TPB);
        const unsigned char* Abuf = &smem[cur][0];
        const int* segc = &seg[cur][0];

        // ---- B: MFMA (bias in C-init); no prefetch regs live here ----
        f32x4 acc[4][4];
        #pragma unroll
        for (int nf = 0; nf < 4; ++nf) {
            float bb = bias[nf];
            #pragma unroll
            for (int mf = 0; mf < 4; ++mf)
                acc[mf][nf] = (f32x4){bb, bb, bb, bb};
        }
        #pragma unroll
        for (int ks = 0; ks < 4; ++ks) {
            const int k0 = ks * 32 + lhi * 8;
            bf16x8 bfrag[4];
            #pragma unroll
            for (int nf = 0; nf < 4; ++nf) {
                int n = wv * 64 + nf * 16 + l15;
                bfrag[nf] = *(const bf16x8*)(W1b + n * HDIM + k0);
            }
            bf16x8 afrag[4];
            #pragma unroll
            for (int mf = 0; mf < 4; ++mf) {
                int m = mf * 16 + l15;
                int boff = m * 256 + ((k0 * 2) ^ ((m & 7) << 4));
                afrag[mf] = *(const bf16x8*)(Abuf + boff);
            }
            #pragma unroll
            for (int mf = 0; mf < 4; ++mf)
                #pragma unroll
                for (int nf = 0; nf < 4; ++nf)
                    acc[mf][nf] = __builtin_amdgcn_mfma_f32_16x16x32_bf16(
                        afrag[mf], bfrag[nf], acc[mf][nf], 0, 0, 0);
        }

        // fence: loads below must not hoist above (would re-create R4's spill)
        __builtin_amdgcn_sched_barrier(0);

        // ---- A: issue prefetch of tile g+1; lands during tanh+reduce ----
        float4 pf[8];
        int sv = 0;
        if (more) {
            const long n1 = (tile0 + g + 1) * BN;
            #pragma unroll
            for (int i = 0; i < 8; ++i) {
                int idx = i * 256 + t; int row = idx >> 5; int c4 = idx & 31;
                pf[i] = *(const float4*)(x + (n1 + row) * HDIM + c4 * 4);
            }
            if (t < BN) sv = batch[is64 ? 2 * (n1 + t) : (n1 + t)];
        }

        // ---- tanh(s) = 1 - 2/(1 + 2^(s*2*log2e)) ----
        #pragma unroll
        for (int mf = 0; mf < 4; ++mf)
            #pragma unroll
            for (int nf = 0; nf < 4; ++nf)
                #pragma unroll
                for (int r = 0; r < 4; ++r) {
                    float e = exp2f(acc[mf][nf][r] * 2.885390081777927f);
                    acc[mf][nf][r] = 1.0f - 2.0f * __builtin_amdgcn_rcpf(1.0f + e);
                }

        // ---- D: in-register segmented reduction (batch sorted) ----
        unsigned long long bmask;
        {
            int s_here = segc[lane];
            int s_prev = (lane > 0) ? segc[lane - 1] : s_here;
            bmask = __ballot(s_here != s_prev);
        }
        int start = 0;
        unsigned long long rem = bmask;
        for (;;) {
            const int end = rem ? (int)__builtin_ctzll(rem) : BN;
            const int sid = segc[start];
            float p0 = 0.f, p1 = 0.f, p2 = 0.f, p3 = 0.f;
            #pragma unroll
            for (int mf = 0; mf < 4; ++mf)
                #pragma unroll
                for (int r = 0; r < 4; ++r) {
                    int row = mf * 16 + lhi * 4 + r;
                    float w = ((unsigned)(row - start) < (unsigned)(end - start)) ? 1.0f : 0.0f;
                    p0 = fmaf(w, acc[mf][0][r], p0);
                    p1 = fmaf(w, acc[mf][1][r], p1);
                    p2 = fmaf(w, acc[mf][2][r], p2);
                    p3 = fmaf(w, acc[mf][3][r], p3);
                }
            p0 += __shfl_xor(p0, 16); p0 += __shfl_xor(p0, 32);
            p1 += __shfl_xor(p1, 16); p1 += __shfl_xor(p1, 32);
            p2 += __shfl_xor(p2, 16); p2 += __shfl_xor(p2, 32);
            p3 += __shfl_xor(p3, 16); p3 += __shfl_xor(p3, 32);
            if (lhi == 0) {
                float* base = sumx + (long)sid * ODIM + wv * 64 + l15;
                atomicAdd(base +  0, p0);
                atomicAdd(base + 16, p1);
                atomicAdd(base + 32, p2);
                atomicAdd(base + 48, p3);
            }
            if (rem == 0) break;
            start = end;
            rem &= rem - 1;
        }

        // ---- C: land prefetched tile into the other buffer ----
        if (more) {
            unsigned char* Wbuf = &smem[cur ^ 1][0];
            #pragma unroll
            for (int i = 0; i < 8; ++i) {
                int idx = i * 256 + t; int row = idx >> 5; int c4 = idx & 31;
                u32x2 p; p.x = pk_bf16(pf[i].x, pf[i].y); p.y = pk_bf16(pf[i].z, pf[i].w);
                int boff = row * 256 + ((c4 * 8) ^ ((row & 7) << 4));
                *(u32x2*)(Wbuf + boff) = p;
            }
            if (t < BN) seg[cur ^ 1][t] = sv;
        }
        __syncthreads();
        cur ^= 1;
    }
}

// y[g][h] = b2[h] + sum_o sumx[g][o] * W2[h][o]   (fp32, 268 MFLOP)
__global__ __launch_bounds__(256)
void stage2(const float* __restrict__ sumx, const float* __restrict__ W2,
            const float* __restrict__ b2, float* __restrict__ y) {
    __shared__ float sx[16 * 256];
    const int t = threadIdx.x;
    const long g0 = (long)blockIdx.x * 16;
    #pragma unroll
    for (int i = 0; i < 16; ++i)
        sx[i * 256 + t] = sumx[(g0 + i) * 256 + t];
    __syncthreads();
    const int h = t & 127;
    const int gl0 = (t >> 7) * 8;
    float acc[8] = {0, 0, 0, 0, 0, 0, 0, 0};
    const float* w = W2 + h * 256;
    for (int o4 = 0; o4 < 64; ++o4) {
        float4 wvv = *(const float4*)(w + o4 * 4);
        #pragma unroll
        for (int gl = 0; gl < 8; ++gl) {
            const float* sr = &sx[(gl0 + gl) * 256 + o4 * 4];
            acc[gl] += sr[0] * wvv.x + sr[1] * wvv.y + sr[2] * wvv.z + sr[3] * wvv.w;
        }
    }
    float bb = b2[h];
    #pragma unroll
    for (int gl = 0; gl < 8; ++gl)
        y[(g0 + gl0 + gl) * 128 + h] = acc[gl] + bb;
}

extern "C" void kernel_launch(void* const* d_in, const int* in_sizes, int n_in,
                              void* d_out, int out_size, void* d_ws, size_t ws_size,
                              hipStream_t stream) {
    const float* x   = (const float*)d_in[0];
    const int* batch = (const int*)d_in[1];
    const float* W1  = (const float*)d_in[2];
    const float* b1  = (const float*)d_in[3];
    const float* W2  = (const float*)d_in[4];
    const float* b2  = (const float*)d_in[5];
    float* y = (float*)d_out;

    float* sumx = (float*)d_ws;                                                     // 4 MB
    unsigned short* W1b = (unsigned short*)((char*)d_ws + (size_t)NSEG * ODIM * 4); // 64 KB

    zero_convert<<<dim3(NSEG), dim3(256), 0, stream>>>(W1, (unsigned int*)W1b, sumx);
    stage1<<<dim3(GRID1), dim3(256), 0, stream>>>(x, batch, W1b, b1, sumx);
    stage2<<<dim3(NSEG / 16), dim3(256), 0, stream>>>(sumx, W2, b2, y);
}

// Round 6
// 232.987 us; speedup vs baseline: 2.1859x; 2.1859x over previous
//
#include <hip/hip_runtime.h>
#include <hip/hip_bf16.h>

#define NTOT 1048576
#define NSEG 4096
#define HDIM 128
#define ODIM 256
#define BN   64
#define GRID1 1024
#define TPB  (NTOT / (BN * GRID1))   // 16 tiles per block

typedef __attribute__((ext_vector_type(8))) short bf16x8;
typedef __attribute__((ext_vector_type(4))) float f32x4;
typedef __attribute__((ext_vector_type(4))) unsigned int u32x4;

typedef const __attribute__((address_space(1))) unsigned int* gp_t;
typedef __attribute__((address_space(3))) unsigned int* lp_t;

__device__ __forceinline__ unsigned short f32_to_bf16_rne(float f) {
    unsigned int u = __builtin_bit_cast(unsigned int, f);
    return (unsigned short)((u + 0x7fffu + ((u >> 16) & 1u)) >> 16);
}
__device__ __forceinline__ unsigned int pk_bf16(float lo, float hi) {
    return ((unsigned int)f32_to_bf16_rne(hi) << 16) | f32_to_bf16_rne(lo);
}

// zero sumx (1M floats) + convert W1 (32768 f32 -> 16384 packed u32), one dispatch
__global__ void zero_convert(const float* __restrict__ W1, unsigned int* __restrict__ W1b,
                             float* __restrict__ sumx) {
    int gid = blockIdx.x * 256 + threadIdx.x;
    sumx[gid] = 0.0f;
    if (gid < (ODIM * HDIM / 2)) {
        float2 v = *(const float2*)(W1 + 2 * gid);
        W1b[gid] = pk_bf16(v.x, v.y);
    }
}

// Persistent pipelined stage1, DMA-staged (global_load_lds -> no spillable regs).
// Per iter: {issue 8 DMAs for tile g+1 into buf^1} -> {MFMA+cvt from buf (pure LDS,
// W1 frags preloaded in regs)} -> tanh -> in-reg segreduce -> __syncthreads()
// (its vmcnt(0) drain IS the pipeline sync for the DMAs).
__global__ __launch_bounds__(256, 2)
void stage1(const float* __restrict__ x, const int* __restrict__ batch,
            const unsigned short* __restrict__ W1b, const float* __restrict__ b1,
            float* __restrict__ sumx) {
    // fragment-major f32 tiles: 16B chunk (b=ks*8+mf*2+half) lives at chunk idx b*64+lane
    __shared__ __align__(16) float xbuf[2][BN * HDIM];   // 2 x 32 KB
    __shared__ int segAll[TPB * BN];                     // 4 KB

    const int t    = threadIdx.x;
    const int lane = t & 63;
    const int wv   = t >> 6;
    const int l15  = lane & 15;
    const int lhi  = (lane >> 4) & 3;

    // dtype probe: int64 little-endian => odd words (high words) are 0
    const bool is64 = (batch[NTOT - 1] == 0);
    const long r0 = (long)blockIdx.x * (TPB * BN);       // first row of this block

    // seg table for the whole block (once)
    for (int i = t; i < TPB * BN; i += 256) {
        long idx = r0 + i;
        segAll[i] = batch[is64 ? 2 * idx : idx];
    }

    // preload ALL W1 B-fragments (64 VGPR, constant across iters -> no VMEM in compute phase)
    bf16x8 bfr[4][4];   // [nf][ks]
    #pragma unroll
    for (int nf = 0; nf < 4; ++nf)
        #pragma unroll
        for (int ks = 0; ks < 4; ++ks)
            bfr[nf][ks] = *(const bf16x8*)(W1b + (wv * 64 + nf * 16 + l15) * HDIM + ks * 32 + lhi * 8);

    float bias[4];
    #pragma unroll
    for (int nf = 0; nf < 4; ++nf) bias[nf] = b1[wv * 64 + nf * 16 + l15];

    // DMA source byte-offsets within a 32KB tile (pre-permuted global -> fragment-major LDS)
    // chunk id = (wv*8+j)*64 + lane ; b = wv*8+j ; half=b&1, mf=(b>>1)&3, ks=b>>3
    // row = mf*16 + l15 ; c4 = ks*8 + lhi*2 + half ; byte = row*512 + c4*16
    int doff[8];
    #pragma unroll
    for (int j = 0; j < 8; ++j) {
        int b   = wv * 8 + j;
        int row = ((b >> 1) & 3) * 16 + l15;
        int c4  = (b >> 3) * 8 + lhi * 2 + (b & 1);
        doff[j] = row * 512 + c4 * 16;
    }

    const char* xb = (const char*)x + (size_t)r0 * (HDIM * 4);

    // prologue: DMA tile 0 -> xbuf[0]
    #pragma unroll
    for (int j = 0; j < 8; ++j)
        __builtin_amdgcn_global_load_lds((gp_t)(xb + doff[j]),
                                         (lp_t)(&xbuf[0][(wv * 8 + j) * 64 * 4]), 16, 0, 0);
    __syncthreads();

    for (int g = 0; g < TPB; ++g) {
        const int nb = g & 1;

        // issue DMA prefetch of tile g+1 into the other buffer (freed by last barrier)
        if (g + 1 < TPB) {
            const char* src = xb + (size_t)(g + 1) * (BN * HDIM * 4);
            #pragma unroll
            for (int j = 0; j < 8; ++j)
                __builtin_amdgcn_global_load_lds((gp_t)(src + doff[j]),
                                                 (lp_t)(&xbuf[nb ^ 1][(wv * 8 + j) * 64 * 4]), 16, 0, 0);
        }

        // ---- MFMA from xbuf[nb]: conflict-free consecutive-lane ds_read_b128 + cvt ----
        f32x4 acc[4][4];
        #pragma unroll
        for (int nf = 0; nf < 4; ++nf) {
            float bb = bias[nf];
            #pragma unroll
            for (int mf = 0; mf < 4; ++mf)
                acc[mf][nf] = (f32x4){bb, bb, bb, bb};
        }
        const f32x4* fb = (const f32x4*)&xbuf[nb][0];
        #pragma unroll
        for (int ks = 0; ks < 4; ++ks) {
            #pragma unroll
            for (int mf = 0; mf < 4; ++mf) {
                f32x4 u = fb[(ks * 8 + mf * 2) * 64 + lane];
                f32x4 v = fb[(ks * 8 + mf * 2 + 1) * 64 + lane];
                u32x4 w;
                w.x = pk_bf16(u.x, u.y); w.y = pk_bf16(u.z, u.w);
                w.z = pk_bf16(v.x, v.y); w.w = pk_bf16(v.z, v.w);
                bf16x8 af = __builtin_bit_cast(bf16x8, w);
                #pragma unroll
                for (int nf = 0; nf < 4; ++nf)
                    acc[mf][nf] = __builtin_amdgcn_mfma_f32_16x16x32_bf16(af, bfr[nf][ks], acc[mf][nf], 0, 0, 0);
            }
        }

        // ---- tanh(s) = 1 - 2/(1 + 2^(s*2*log2e)) ----
        #pragma unroll
        for (int mf = 0; mf < 4; ++mf)
            #pragma unroll
            for (int nf = 0; nf < 4; ++nf)
                #pragma unroll
                for (int r = 0; r < 4; ++r) {
                    float e = exp2f(acc[mf][nf][r] * 2.885390081777927f);
                    acc[mf][nf][r] = 1.0f - 2.0f * __builtin_amdgcn_rcpf(1.0f + e);
                }

        // ---- in-register segmented reduction (batch sorted) ----
        const int* segc = &segAll[g * 64];
        unsigned long long bmask;
        {
            int s_here = segc[lane];
            int s_prev = (lane > 0) ? segc[lane - 1] : s_here;
            bmask = __ballot(s_here != s_prev);
        }
        int start = 0;
        unsigned long long rem = bmask;
        for (;;) {
            const int end = rem ? (int)__builtin_ctzll(rem) : BN;
            const int sid = segc[start];
            float p0 = 0.f, p1 = 0.f, p2 = 0.f, p3 = 0.f;
            #pragma unroll
            for (int mf = 0; mf < 4; ++mf)
                #pragma unroll
                for (int r = 0; r < 4; ++r) {
                    int row = mf * 16 + lhi * 4 + r;
                    float w = ((unsigned)(row - start) < (unsigned)(end - start)) ? 1.0f : 0.0f;
                    p0 = fmaf(w, acc[mf][0][r], p0);
                    p1 = fmaf(w, acc[mf][1][r], p1);
                    p2 = fmaf(w, acc[mf][2][r], p2);
                    p3 = fmaf(w, acc[mf][3][r], p3);
                }
            p0 += __shfl_xor(p0, 16); p0 += __shfl_xor(p0, 32);
            p1 += __shfl_xor(p1, 16); p1 += __shfl_xor(p1, 32);
            p2 += __shfl_xor(p2, 16); p2 += __shfl_xor(p2, 32);
            p3 += __shfl_xor(p3, 16); p3 += __shfl_xor(p3, 32);
            if (lhi == 0) {
                float* base = sumx + (long)sid * ODIM + wv * 64 + l15;
                atomicAdd(base +  0, p0);
                atomicAdd(base + 16, p1);
                atomicAdd(base + 32, p2);
                atomicAdd(base + 48, p3);
            }
            if (rem == 0) break;
            start = end;
            rem &= rem - 1;
        }

        // barrier: waits lgkm (reads of xbuf[nb] done) AND vmcnt(0) (DMAs for g+1 landed)
        __syncthreads();
    }
}

// y[g][h] = b2[h] + sum_o sumx[g][o] * W2[h][o]   (fp32, 268 MFLOP)
__global__ __launch_bounds__(256)
void stage2(const float* __restrict__ sumx, const float* __restrict__ W2,
            const float* __restrict__ b2, float* __restrict__ y) {
    __shared__ float sx[16 * 256];
    const int t = threadIdx.x;
    const long g0 = (long)blockIdx.x * 16;
    #pragma unroll
    for (int i = 0; i < 16; ++i)
        sx[i * 256 + t] = sumx[(g0 + i) * 256 + t];
    __syncthreads();
    const int h = t & 127;
    const int gl0 = (t >> 7) * 8;
    float acc[8] = {0, 0, 0, 0, 0, 0, 0, 0};
    const float* w = W2 + h * 256;
    for (int o4 = 0; o4 < 64; ++o4) {
        float4 wvv = *(const float4*)(w + o4 * 4);
        #pragma unroll
        for (int gl = 0; gl < 8; ++gl) {
            const float* sr = &sx[(gl0 + gl) * 256 + o4 * 4];
            acc[gl] += sr[0] * wvv.x + sr[1] * wvv.y + sr[2] * wvv.z + sr[3] * wvv.w;
        }
    }
    float bb = b2[h];
    #pragma unroll
    for (int gl = 0; gl < 8; ++gl)
        y[(g0 + gl0 + gl) * 128 + h] = acc[gl] + bb;
}

extern "C" void kernel_launch(void* const* d_in, const int* in_sizes, int n_in,
                              void* d_out, int out_size, void* d_ws, size_t ws_size,
                              hipStream_t stream) {
    const float* x   = (const float*)d_in[0];
    const int* batch = (const int*)d_in[1];
    const float* W1  = (const float*)d_in[2];
    const float* b1  = (const float*)d_in[3];
    const float* W2  = (const float*)d_in[4];
    const float* b2  = (const float*)d_in[5];
    float* y = (float*)d_out;

    float* sumx = (float*)d_ws;                                                     // 4 MB
    unsigned short* W1b = (unsigned short*)((char*)d_ws + (size_t)NSEG * ODIM * 4); // 64 KB

    zero_convert<<<dim3(NSEG), dim3(256), 0, stream>>>(W1, (unsigned int*)W1b, sumx);
    stage1<<<dim3(GRID1), dim3(256), 0, stream>>>(x, batch, W1b, b1, sumx);
    stage2<<<dim3(NSEG / 16), dim3(256), 0, stream>>>(sumx, W2, b2, y);
}